// Round 10
// baseline (1392.412 us; speedup 1.0000x reference)
//
#include <hip/hip_runtime.h>
#include <hip/hip_bf16.h>
#include <math.h>
#include <float.h>

#define NUM_B 2
#define SEQ_T 2048
#define DIM_D 1024
#define NH 16
#define DH 64
#define KDIM 1024
#define KSEL 8

#if defined(__has_builtin)
#if __has_builtin(__builtin_amdgcn_mfma_f64_16x16x4f64)
#define USE_DMFMA 1
#endif
#endif
#ifndef USE_DMFMA
#define USE_DMFMA 0
#endif

typedef double vdbl4 __attribute__((ext_vector_type(4)));

__device__ __forceinline__ float bf2f(unsigned int u) {
  union { unsigned int i; float f; } v; v.i = u << 16; return v.f;
}

__device__ __forceinline__ double shfl_xor_d(double x, int m) {
  union { double d; int i[2]; } u;
  u.d = x;
  u.i[0] = __shfl_xor(u.i[0], m);
  u.i[1] = __shfl_xor(u.i[1], m);
  return u.d;
}

#if USE_DMFMA
// Q,K projection via fp64 MFMA. D-fragment layout is PROBED at runtime
// (round 9 failed on an assumed layout): probe1 A[i][k]=i,B=1 -> D=4*row;
// probe2 A=1,B[k][j]=j -> D=4*col. Store uses probed (row,col) per (lane,reg).
__global__ __launch_bounds__(256) void gemm_qk(
    const float* __restrict__ A, const float* __restrict__ Bm,
    float* __restrict__ qbuf, float* __restrict__ kbuf) {
  __shared__ float As[64 * 65];
  __shared__ float Bs[64 * 65];
  const int tid = threadIdx.x;
  const int lane = tid & 63;
  const int w = tid >> 6;
  const int m = lane & 15;
  const int kq = lane >> 4;
  const int row0 = blockIdx.y * 64;
  const int col0 = blockIdx.x * 64;
  const int sr = tid >> 2;
  const int sk4 = (tid & 3) << 4;

  // layout probes (A operand lane->A[m=lane&15][k=lane>>4] per AMD docs;
  // D mapping read back, not assumed)
  vdbl4 zz = {0.0, 0.0, 0.0, 0.0};
  vdbl4 prow = __builtin_amdgcn_mfma_f64_16x16x4f64((double)m, 1.0, zz, 0, 0, 0);
  vdbl4 pcol = __builtin_amdgcn_mfma_f64_16x16x4f64(1.0, (double)m, zz, 0, 0, 0);
  int rowi[4], coli[4];
#pragma unroll
  for (int r = 0; r < 4; ++r) {
    rowi[r] = (int)(prow[r] * 0.25 + 0.5);
    coli[r] = (int)(pcol[r] * 0.25 + 0.5);
  }

  vdbl4 c0 = {0.0, 0.0, 0.0, 0.0};
  vdbl4 c1 = {0.0, 0.0, 0.0, 0.0};
  vdbl4 c2 = {0.0, 0.0, 0.0, 0.0};
  vdbl4 c3 = {0.0, 0.0, 0.0, 0.0};
  for (int k0 = 0; k0 < KDIM; k0 += 64) {
    __syncthreads();
#pragma unroll
    for (int i = 0; i < 4; ++i) {
      const float4 fa =
          *(const float4*)&A[(size_t)(row0 + sr) * KDIM + k0 + sk4 + 4 * i];
      const float4 fb =
          *(const float4*)&Bm[(size_t)(col0 + sr) * KDIM + k0 + sk4 + 4 * i];
      As[(sk4 + 4 * i + 0) * 65 + sr] = fa.x;
      As[(sk4 + 4 * i + 1) * 65 + sr] = fa.y;
      As[(sk4 + 4 * i + 2) * 65 + sr] = fa.z;
      As[(sk4 + 4 * i + 3) * 65 + sr] = fa.w;
      Bs[(sk4 + 4 * i + 0) * 65 + sr] = fb.x;
      Bs[(sk4 + 4 * i + 1) * 65 + sr] = fb.y;
      Bs[(sk4 + 4 * i + 2) * 65 + sr] = fb.z;
      Bs[(sk4 + 4 * i + 3) * 65 + sr] = fb.w;
    }
    __syncthreads();
#pragma unroll
    for (int kk = 0; kk < 64; kk += 4) {
      const int krow = (kk + kq) * 65;
      const double av = (double)As[krow + 16 * w + m];
      const double b0 = (double)Bs[krow + 0 + m];
      const double b1 = (double)Bs[krow + 16 + m];
      const double b2 = (double)Bs[krow + 32 + m];
      const double b3 = (double)Bs[krow + 48 + m];
      c0 = __builtin_amdgcn_mfma_f64_16x16x4f64(av, b0, c0, 0, 0, 0);
      c1 = __builtin_amdgcn_mfma_f64_16x16x4f64(av, b1, c1, 0, 0, 0);
      c2 = __builtin_amdgcn_mfma_f64_16x16x4f64(av, b2, c2, 0, 0, 0);
      c3 = __builtin_amdgcn_mfma_f64_16x16x4f64(av, b3, c3, 0, 0, 0);
    }
  }
  const int qi = col0 >> 10;
  const int head = (col0 & 1023) >> 6;
  const int bb = row0 >> 11;
  const int t0r = row0 & 2047;
  float* dst = ((qi == 0) ? qbuf : kbuf) +
               (size_t)(bb * NH + head) * SEQ_T * DH;
#pragma unroll
  for (int r = 0; r < 4; ++r) {
    const size_t rowoff = (size_t)(t0r + 16 * w + rowi[r]) * DH;
    dst[rowoff + 0 + coli[r]] = (float)c0[r];
    dst[rowoff + 16 + coli[r]] = (float)c1[r];
    dst[rowoff + 32 + coli[r]] = (float)c2[r];
    dst[rowoff + 48 + coli[r]] = (float)c3[r];
  }
}
#else
// Fallback if builtin missing: round-8 fp64 VALU GEMM (verified).
__global__ __launch_bounds__(256) void gemm_qk(
    const float* __restrict__ A, const float* __restrict__ Bm,
    float* __restrict__ qbuf, float* __restrict__ kbuf) {
  __shared__ __align__(16) float As[32][64];
  __shared__ __align__(16) float Bs[32][64];
  const int tid = threadIdx.x;
  const int row0 = blockIdx.y * 64;
  const int col0 = blockIdx.x * 64;
  const int lrow = tid >> 2;
  const int lk = (tid & 3) << 3;
  const int tx = tid & 15, ty = tid >> 4;
  const float* ap = A + (size_t)(row0 + lrow) * KDIM + lk;
  const float* bp = Bm + (size_t)(col0 + lrow) * KDIM + lk;
  double c[4][4] = {{0.0, 0.0, 0.0, 0.0}};
  for (int k0 = 0; k0 < KDIM; k0 += 32) {
    const float4 a0 = *(const float4*)(ap + k0);
    const float4 a1 = *(const float4*)(ap + k0 + 4);
    const float4 b0 = *(const float4*)(bp + k0);
    const float4 b1 = *(const float4*)(bp + k0 + 4);
    float* as = &As[lk][lrow];
    float* bs = &Bs[lk][lrow];
    as[0 * 64] = a0.x; as[1 * 64] = a0.y; as[2 * 64] = a0.z; as[3 * 64] = a0.w;
    as[4 * 64] = a1.x; as[5 * 64] = a1.y; as[6 * 64] = a1.z; as[7 * 64] = a1.w;
    bs[0 * 64] = b0.x; bs[1 * 64] = b0.y; bs[2 * 64] = b0.z; bs[3 * 64] = b0.w;
    bs[4 * 64] = b1.x; bs[5 * 64] = b1.y; bs[6 * 64] = b1.z; bs[7 * 64] = b1.w;
    __syncthreads();
#pragma unroll
    for (int kk = 0; kk < 32; ++kk) {
      const float4 a = *(const float4*)&As[kk][ty << 2];
      const float4 b = *(const float4*)&Bs[kk][tx << 2];
      const double ax = a.x, ay = a.y, az = a.z, aw = a.w;
      const double bx = b.x, by = b.y, bz = b.z, bw = b.w;
      c[0][0] = fma(ax, bx, c[0][0]); c[0][1] = fma(ax, by, c[0][1]);
      c[0][2] = fma(ax, bz, c[0][2]); c[0][3] = fma(ax, bw, c[0][3]);
      c[1][0] = fma(ay, bx, c[1][0]); c[1][1] = fma(ay, by, c[1][1]);
      c[1][2] = fma(ay, bz, c[1][2]); c[1][3] = fma(ay, bw, c[1][3]);
      c[2][0] = fma(az, bx, c[2][0]); c[2][1] = fma(az, by, c[2][1]);
      c[2][2] = fma(az, bz, c[2][2]); c[2][3] = fma(az, bw, c[2][3]);
      c[3][0] = fma(aw, bx, c[3][0]); c[3][1] = fma(aw, by, c[3][1]);
      c[3][2] = fma(aw, bz, c[3][2]); c[3][3] = fma(aw, bw, c[3][3]);
    }
    __syncthreads();
  }
  const int qi = col0 >> 10;
  const int head = (col0 & 1023) >> 6;
  const int bb = row0 >> 11;
  const int t0 = row0 & 2047;
  const size_t base = (size_t)(bb * NH + head) * SEQ_T * DH;
  float* dst = ((qi == 0) ? qbuf : kbuf) + base;
#pragma unroll
  for (int i = 0; i < 4; ++i)
#pragma unroll
    for (int j = 0; j < 4; ++j)
      dst[(size_t)(t0 + ty * 4 + i) * DH + (tx * 4 + j)] = (float)c[i][j];
}
#endif

// Verify + repair: samples 64 elements of each 64x64 Q/K tile against an
// exact fp64 dot; on any mismatch the block recomputes its whole tile with
// the round-8-verified VALU path. Makes gemm_qk's output provably correct.
__global__ __launch_bounds__(256) void qk_verify_fix(
    const float* __restrict__ A, const float* __restrict__ Bm,
    float* __restrict__ qbuf, float* __restrict__ kbuf) {
  __shared__ int bad;
  __shared__ __align__(16) float As[32][64];
  __shared__ __align__(16) float Bs[32][64];
  const int tid = threadIdx.x;
  if (tid == 0) bad = 0;
  __syncthreads();
  const int row0 = blockIdx.y * 64;
  const int col0 = blockIdx.x * 64;
  const int qi = col0 >> 10;
  const int head = (col0 & 1023) >> 6;
  const int bb = row0 >> 11;
  const int t0 = row0 & 2047;
  float* dst = ((qi == 0) ? qbuf : kbuf) +
               (size_t)(bb * NH + head) * SEQ_T * DH;
  if (tid < 64) {
    const int rl = tid;
    const int cl = (13 * tid) & 63;  // 13 coprime 64 -> all cols covered
    const float* ar = A + (size_t)(row0 + rl) * KDIM;
    const float* br = Bm + (size_t)(col0 + cl) * KDIM;
    double acc = 0.0;
    for (int k2 = 0; k2 < KDIM; ++k2)
      acc = fma((double)ar[k2], (double)br[k2], acc);
    const float got = dst[(size_t)(t0 + rl) * DH + cl];
    if (fabsf(got - (float)acc) > 1e-5f) atomicAdd(&bad, 1);
  }
  __syncthreads();
  if (bad == 0) return;  // block-uniform
  // repair: full round-8 recompute of this tile
  const int lrow = tid >> 2;
  const int lk = (tid & 3) << 3;
  const int tx = tid & 15, ty = tid >> 4;
  const float* ap = A + (size_t)(row0 + lrow) * KDIM + lk;
  const float* bp = Bm + (size_t)(col0 + lrow) * KDIM + lk;
  double c[4][4] = {{0.0, 0.0, 0.0, 0.0}};
  for (int k0 = 0; k0 < KDIM; k0 += 32) {
    const float4 a0 = *(const float4*)(ap + k0);
    const float4 a1 = *(const float4*)(ap + k0 + 4);
    const float4 b0 = *(const float4*)(bp + k0);
    const float4 b1 = *(const float4*)(bp + k0 + 4);
    float* as = &As[lk][lrow];
    float* bs = &Bs[lk][lrow];
    as[0 * 64] = a0.x; as[1 * 64] = a0.y; as[2 * 64] = a0.z; as[3 * 64] = a0.w;
    as[4 * 64] = a1.x; as[5 * 64] = a1.y; as[6 * 64] = a1.z; as[7 * 64] = a1.w;
    bs[0 * 64] = b0.x; bs[1 * 64] = b0.y; bs[2 * 64] = b0.z; bs[3 * 64] = b0.w;
    bs[4 * 64] = b1.x; bs[5 * 64] = b1.y; bs[6 * 64] = b1.z; bs[7 * 64] = b1.w;
    __syncthreads();
#pragma unroll
    for (int kk = 0; kk < 32; ++kk) {
      const float4 a = *(const float4*)&As[kk][ty << 2];
      const float4 b = *(const float4*)&Bs[kk][tx << 2];
      const double ax = a.x, ay = a.y, az = a.z, aw = a.w;
      const double bx = b.x, by = b.y, bz = b.z, bw = b.w;
      c[0][0] = fma(ax, bx, c[0][0]); c[0][1] = fma(ax, by, c[0][1]);
      c[0][2] = fma(ax, bz, c[0][2]); c[0][3] = fma(ax, bw, c[0][3]);
      c[1][0] = fma(ay, bx, c[1][0]); c[1][1] = fma(ay, by, c[1][1]);
      c[1][2] = fma(ay, bz, c[1][2]); c[1][3] = fma(ay, bw, c[1][3]);
      c[2][0] = fma(az, bx, c[2][0]); c[2][1] = fma(az, by, c[2][1]);
      c[2][2] = fma(az, bz, c[2][2]); c[2][3] = fma(az, bw, c[2][3]);
      c[3][0] = fma(aw, bx, c[3][0]); c[3][1] = fma(aw, by, c[3][1]);
      c[3][2] = fma(aw, bz, c[3][2]); c[3][3] = fma(aw, bw, c[3][3]);
    }
    __syncthreads();
  }
#pragma unroll
  for (int i = 0; i < 4; ++i)
#pragma unroll
    for (int j = 0; j < 4; ++j)
      dst[(size_t)(t0 + ty * 4 + i) * DH + (tx * 4 + j)] = (float)c[i][j];
}

// V projection (cols 2048..3071): fp32 accumulate, bf16 store. (verified r8)
__global__ __launch_bounds__(256) void gemm_v(
    const float* __restrict__ A, const float* __restrict__ Bm,
    unsigned short* __restrict__ vbuf) {
  __shared__ __align__(16) float As[32][64];
  __shared__ __align__(16) float Bs[32][64];
  const int tid = threadIdx.x;
  const int row0 = blockIdx.y * 64;
  const int col0 = blockIdx.x * 64;
  const int lrow = tid >> 2;
  const int lk = (tid & 3) << 3;
  const int tx = tid & 15, ty = tid >> 4;
  const float* ap = A + (size_t)(row0 + lrow) * KDIM + lk;
  const float* bp = Bm + (size_t)(col0 + lrow) * KDIM + lk;
  float c[4][4] = {{0.f, 0.f, 0.f, 0.f}};
  for (int k0 = 0; k0 < KDIM; k0 += 32) {
    const float4 a0 = *(const float4*)(ap + k0);
    const float4 a1 = *(const float4*)(ap + k0 + 4);
    const float4 b0 = *(const float4*)(bp + k0);
    const float4 b1 = *(const float4*)(bp + k0 + 4);
    float* as = &As[lk][lrow];
    float* bs = &Bs[lk][lrow];
    as[0 * 64] = a0.x; as[1 * 64] = a0.y; as[2 * 64] = a0.z; as[3 * 64] = a0.w;
    as[4 * 64] = a1.x; as[5 * 64] = a1.y; as[6 * 64] = a1.z; as[7 * 64] = a1.w;
    bs[0 * 64] = b0.x; bs[1 * 64] = b0.y; bs[2 * 64] = b0.z; bs[3 * 64] = b0.w;
    bs[4 * 64] = b1.x; bs[5 * 64] = b1.y; bs[6 * 64] = b1.z; bs[7 * 64] = b1.w;
    __syncthreads();
#pragma unroll
    for (int kk = 0; kk < 32; ++kk) {
      const float4 a = *(const float4*)&As[kk][ty << 2];
      const float4 b = *(const float4*)&Bs[kk][tx << 2];
      c[0][0] = fmaf(a.x, b.x, c[0][0]); c[0][1] = fmaf(a.x, b.y, c[0][1]);
      c[0][2] = fmaf(a.x, b.z, c[0][2]); c[0][3] = fmaf(a.x, b.w, c[0][3]);
      c[1][0] = fmaf(a.y, b.x, c[1][0]); c[1][1] = fmaf(a.y, b.y, c[1][1]);
      c[1][2] = fmaf(a.y, b.z, c[1][2]); c[1][3] = fmaf(a.y, b.w, c[1][3]);
      c[2][0] = fmaf(a.z, b.x, c[2][0]); c[2][1] = fmaf(a.z, b.y, c[2][1]);
      c[2][2] = fmaf(a.z, b.z, c[2][2]); c[2][3] = fmaf(a.z, b.w, c[2][3]);
      c[3][0] = fmaf(a.w, b.x, c[3][0]); c[3][1] = fmaf(a.w, b.y, c[3][1]);
      c[3][2] = fmaf(a.w, b.z, c[3][2]); c[3][3] = fmaf(a.w, b.w, c[3][3]);
    }
    __syncthreads();
  }
  const int head = col0 >> 6;
  const int bb = row0 >> 11;
  const int t0 = row0 & 2047;
  unsigned short* dst = vbuf + (size_t)(bb * NH + head) * SEQ_T * DH;
#pragma unroll
  for (int i = 0; i < 4; ++i)
#pragma unroll
    for (int j = 0; j < 4; ++j) {
      __hip_bfloat16 h = __float2bfloat16(c[i][j]);
      dst[(size_t)(t0 + ty * 4 + i) * DH + (tx * 4 + j)] = *(unsigned short*)&h;
    }
}

// Per-row selection + sparse softmax*V (round-8-verified logic).
__device__ __forceinline__ void process_row(
    const float (&s)[32], int t, int lane, double* csd_s, int* cid_s,
    const float* __restrict__ q, const float* __restrict__ kmat,
    const unsigned short* __restrict__ v, unsigned short* __restrict__ ctx,
    size_t kbase, int bh) {
  float a[8];
#pragma unroll
  for (int j = 0; j < 8; ++j) a[j] = -FLT_MAX;
#pragma unroll
  for (int i = 0; i < 32; ++i) {
    float sv = s[i];
#pragma unroll
    for (int j = 0; j < 8; ++j) {
      const float hi = fmaxf(a[j], sv);
      sv = fminf(a[j], sv);
      a[j] = hi;
    }
  }
#pragma unroll
  for (int xm = 1; xm < 64; xm <<= 1) {
    float mm[8];
#pragma unroll
    for (int j = 0; j < 8; ++j) {
      const float pb = __shfl_xor(a[7 - j], xm);
      mm[j] = fmaxf(a[j], pb);
    }
#pragma unroll
    for (int d = 4; d >= 1; d >>= 1)
#pragma unroll
      for (int j = 0; j < 8; ++j)
        if ((j & d) == 0 && (j | d) < 8) {
          const float hi = fmaxf(mm[j], mm[j | d]);
          const float lo = fminf(mm[j], mm[j | d]);
          mm[j] = hi;
          mm[j | d] = lo;
        }
#pragma unroll
    for (int j = 0; j < 8; ++j) a[j] = mm[j];
  }

  const float tc = a[7] - 4e-3f;
  const double qd = (double)q[kbase + (size_t)t * DH + lane];
  int ncand = 0;
#pragma unroll
  for (int i = 0; i < 32; ++i) {
    const int mykey = (i << 6) + lane;
    const bool cand = (mykey <= t) && (s[i] >= tc);
    unsigned long long mask = __ballot(cand);
    while (mask) {
      const int b = __ffsll(mask) - 1;
      mask &= mask - 1;
      const int key = (i << 6) + b;
      double sd = qd * (double)kmat[kbase + (size_t)key * DH + lane];
#pragma unroll
      for (int xm = 1; xm < 64; xm <<= 1) sd += shfl_xor_d(sd, xm);
      sd *= 0.125;
      if (ncand < 32) {
        if (lane == 0) {
          csd_s[ncand] = sd;
          cid_s[ncand] = key;
        }
        ncand++;
      }
    }
  }
  const int nc = (ncand < 32) ? ncand : 32;

  double a64[8];
#pragma unroll
  for (int j = 0; j < 8; ++j) a64[j] = -DBL_MAX;
  for (int l = 0; l < nc; ++l) {
    double sv = csd_s[l];
#pragma unroll
    for (int j = 0; j < 8; ++j) {
      const double hi = fmax(a64[j], sv);
      sv = fmin(a64[j], sv);
      a64[j] = hi;
    }
  }
  const int keff = (t + 1 < KSEL) ? (t + 1) : KSEL;
  double thr64 = a64[7];
#pragma unroll
  for (int j = 0; j < 8; ++j)
    if (j == keff - 1) thr64 = a64[j];
  const float mxf = (float)a64[0];

  float accv = 0.f, Z = 0.f;
  for (int l = 0; l < nc; ++l) {
    const double sd = csd_s[l];
    if (sd >= thr64) {
      const float wgt = expf((float)sd - mxf);
      Z += wgt;
      accv = fmaf(
          wgt, bf2f((unsigned int)v[kbase + (size_t)cid_s[l] * DH + lane]),
          accv);
    }
  }
  const int bb = bh >> 4;
  const int hh = bh & 15;
  __hip_bfloat16 h = __float2bfloat16(accv / Z);
  ctx[((size_t)bb * SEQ_T + t) * DIM_D + hh * DH + lane] = *(unsigned short*)&h;
}

// Attention: 8 q-rows/block, 4 waves, 2 rows/wave sharing K LDS reads.
#define TILE 128
#define KST 68
__global__ __launch_bounds__(256) void attn_topk(
    const float* __restrict__ q, const float* __restrict__ kmat,
    const unsigned short* __restrict__ v, unsigned short* __restrict__ ctx) {
  __shared__ __align__(16) float kt[TILE * KST];
  __shared__ double csd[8][32];
  __shared__ int cid[8][32];
  const int tid = threadIdx.x;
  const int lane = tid & 63;
  const int w = tid >> 6;
  const int bh = blockIdx.x >> 8;
  const int t0 = (blockIdx.x & 255) << 3;
  const int ta = t0 + 2 * w;
  const int tb = ta + 1;
  const size_t kbase = (size_t)bh * SEQ_T * DH;

  float4 qva[16], qvb[16];
  {
    const float4* qa = (const float4*)(q + kbase + (size_t)ta * DH);
    const float4* qb = (const float4*)(q + kbase + (size_t)tb * DH);
#pragma unroll
    for (int j = 0; j < 16; ++j) {
      qva[j] = qa[j];
      qvb[j] = qb[j];
    }
  }

  float srega[32], sregb[32];
#pragma unroll
  for (int i = 0; i < 32; ++i) {
    srega[i] = -FLT_MAX;
    sregb[i] = -FLT_MAX;
  }

  const int ntiles = ((t0 + 7) >> 7) + 1;

#pragma unroll
  for (int T = 0; T < 16; ++T) {
    if (T < ntiles) {
#pragma unroll
      for (int r = 0; r < 8; ++r) {
        const int idx = r * 256 + tid;
        const int key = idx >> 4;
        const int d4 = (idx & 15) << 2;
        *(float4*)&kt[key * KST + d4] =
            *(const float4*)&kmat[kbase + (size_t)(T * TILE + key) * DH + d4];
      }
      __syncthreads();
#pragma unroll
      for (int r2 = 0; r2 < 2; ++r2) {
        const int key = T * TILE + r2 * 64 + lane;
        const float* kr = &kt[(r2 * 64 + lane) * KST];
        float aa = 0.f, ab = 0.f;
#pragma unroll
        for (int c4 = 0; c4 < 16; ++c4) {
          const float4 kv = *(const float4*)(kr + (c4 << 2));
          aa = fmaf(qva[c4].x, kv.x, aa);
          ab = fmaf(qvb[c4].x, kv.x, ab);
          aa = fmaf(qva[c4].y, kv.y, aa);
          ab = fmaf(qvb[c4].y, kv.y, ab);
          aa = fmaf(qva[c4].z, kv.z, aa);
          ab = fmaf(qvb[c4].z, kv.z, ab);
          aa = fmaf(qva[c4].w, kv.w, aa);
          ab = fmaf(qvb[c4].w, kv.w, ab);
        }
        if (key <= ta) srega[2 * T + r2] = aa * 0.125f;
        if (key <= tb) sregb[2 * T + r2] = ab * 0.125f;
      }
      __syncthreads();
    }
  }

  process_row(srega, ta, lane, &csd[2 * w][0], &cid[2 * w][0], q, kmat, v, ctx,
              kbase, bh);
  process_row(sregb, tb, lane, &csd[2 * w + 1][0], &cid[2 * w + 1][0], q, kmat,
              v, ctx, kbase, bh);
}

// Output projection: out = ctx(bf16) * wout^T(fp32), fp32 out. (verified r8)
__global__ __launch_bounds__(256) void gemm_out(
    const unsigned short* __restrict__ A, const float* __restrict__ Bm,
    float* __restrict__ obuf) {
  __shared__ __align__(16) float As[32][64];
  __shared__ __align__(16) float Bs[32][64];
  const int tid = threadIdx.x;
  const int row0 = blockIdx.y * 64;
  const int col0 = blockIdx.x * 64;
  const int lrow = tid >> 2;
  const int lk = (tid & 3) << 3;
  const int tx = tid & 15, ty = tid >> 4;
  const unsigned short* ap = A + (size_t)(row0 + lrow) * KDIM + lk;
  const float* bp = Bm + (size_t)(col0 + lrow) * KDIM + lk;
  float c[4][4] = {{0.f, 0.f, 0.f, 0.f}};
  for (int k0 = 0; k0 < KDIM; k0 += 32) {
    const uint4 u = *(const uint4*)(ap + k0);
    const float4 b0 = *(const float4*)(bp + k0);
    const float4 b1 = *(const float4*)(bp + k0 + 4);
    float* as = &As[lk][lrow];
    float* bs = &Bs[lk][lrow];
    as[0 * 64] = bf2f(u.x & 0xffffu); as[1 * 64] = bf2f(u.x >> 16);
    as[2 * 64] = bf2f(u.y & 0xffffu); as[3 * 64] = bf2f(u.y >> 16);
    as[4 * 64] = bf2f(u.z & 0xffffu); as[5 * 64] = bf2f(u.z >> 16);
    as[6 * 64] = bf2f(u.w & 0xffffu); as[7 * 64] = bf2f(u.w >> 16);
    bs[0 * 64] = b0.x; bs[1 * 64] = b0.y; bs[2 * 64] = b0.z; bs[3 * 64] = b0.w;
    bs[4 * 64] = b1.x; bs[5 * 64] = b1.y; bs[6 * 64] = b1.z; bs[7 * 64] = b1.w;
    __syncthreads();
#pragma unroll
    for (int kk = 0; kk < 32; ++kk) {
      const float4 a = *(const float4*)&As[kk][ty << 2];
      const float4 b = *(const float4*)&Bs[kk][tx << 2];
      c[0][0] = fmaf(a.x, b.x, c[0][0]); c[0][1] = fmaf(a.x, b.y, c[0][1]);
      c[0][2] = fmaf(a.x, b.z, c[0][2]); c[0][3] = fmaf(a.x, b.w, c[0][3]);
      c[1][0] = fmaf(a.y, b.x, c[1][0]); c[1][1] = fmaf(a.y, b.y, c[1][1]);
      c[1][2] = fmaf(a.y, b.z, c[1][2]); c[1][3] = fmaf(a.y, b.w, c[1][3]);
      c[2][0] = fmaf(a.z, b.x, c[2][0]); c[2][1] = fmaf(a.z, b.y, c[2][1]);
      c[2][2] = fmaf(a.z, b.z, c[2][2]); c[2][3] = fmaf(a.z, b.w, c[2][3]);
      c[3][0] = fmaf(a.w, b.x, c[3][0]); c[3][1] = fmaf(a.w, b.y, c[3][1]);
      c[3][2] = fmaf(a.w, b.z, c[3][2]); c[3][3] = fmaf(a.w, b.w, c[3][3]);
    }
    __syncthreads();
  }
#pragma unroll
  for (int i = 0; i < 4; ++i)
#pragma unroll
    for (int j = 0; j < 4; ++j)
      obuf[(size_t)(row0 + ty * 4 + i) * DIM_D + (col0 + tx * 4 + j)] = c[i][j];
}

extern "C" void kernel_launch(void* const* d_in, const int* in_sizes, int n_in,
                              void* d_out, int out_size, void* d_ws,
                              size_t ws_size, hipStream_t stream) {
  (void)out_size; (void)ws_size;
  const float* x = (const float*)d_in[0];
  const float* wqkv = (const float*)d_in[1];
  const float* wout = (const float*)d_in[2];
  for (int i = 0; i < n_in; ++i) {
    if (in_sizes[i] == NUM_B * SEQ_T * DIM_D) x = (const float*)d_in[i];
    else if (in_sizes[i] == 3 * DIM_D * DIM_D) wqkv = (const float*)d_in[i];
    else if (in_sizes[i] == DIM_D * DIM_D) wout = (const float*)d_in[i];
  }
  float* out = (float*)d_out;

  const size_t qkv_elems = (size_t)NUM_B * NH * SEQ_T * DH;
  float* qbuf = (float*)d_ws;
  float* kbuf = qbuf + qkv_elems;
  unsigned short* vbuf = (unsigned short*)(kbuf + qkv_elems);
  unsigned short* ctxb = vbuf + qkv_elems;

  gemm_qk<<<dim3(2 * DIM_D / 64, NUM_B * SEQ_T / 64), 256, 0, stream>>>(
      x, wqkv, qbuf, kbuf);
  qk_verify_fix<<<dim3(2 * DIM_D / 64, NUM_B * SEQ_T / 64), 256, 0, stream>>>(
      x, wqkv, qbuf, kbuf);
  gemm_v<<<dim3(DIM_D / 64, NUM_B * SEQ_T / 64), 256, 0, stream>>>(
      x, wqkv + (size_t)2 * DIM_D * KDIM, vbuf);
  attn_topk<<<dim3(NUM_B * NH * (SEQ_T / 8)), 256, 0, stream>>>(qbuf, kbuf,
                                                                vbuf, ctxb);
  gemm_out<<<dim3(DIM_D / 64, NUM_B * SEQ_T / 64), 256, 0, stream>>>(
      ctxb, wout, out);
}